// Round 9
// baseline (16.560 us; speedup 1.0000x reference)
//
#include <hip/hip_runtime.h>

typedef float vf4 __attribute__((ext_vector_type(4)));

// Async global->LDS, 16B per lane, wave-uniform LDS base (HW: base + lane*16).
__device__ __forceinline__ void gload_lds16(const void* g, void* l) {
    __builtin_amdgcn_global_load_lds(
        (const __attribute__((address_space(1))) void*)g,
        (__attribute__((address_space(3))) void*)l,
        16, 0, 0);
}

// One block per 64x64 image, 256 threads.
// Image staged in LDS with ZERO halo rows at lds-row 0 and 65:
// global row r -> lds row r+1 (offset 64 floats). Removes all vertical-halo
// clamping/masking from the compute path (~42 VALU/thread).
// Horizontal halo via __shfl within 16-lane groups (edge lanes zeroed).
// Normal (cacheable) stores: output stays L3-resident across graph replays,
// removing the forced 32 MB/replay HBM write stream that nontemporal caused.
__global__ __launch_bounds__(256) void sobel_v8(
    const float* __restrict__ in,      // (2048,1,64,64)
    const float* __restrict__ weight,  // (1,9)
    const float* __restrict__ wfac_p,  // (1,)
    const float* __restrict__ scale_p, // (1,1)
    float* __restrict__ out)
{
    __shared__ __align__(16) float img[66 * 64];   // rows 0..65, 16.9 KB
    __shared__ float smin[4], smax[4];

    const int tid  = threadIdx.x;
    const int lane = tid & 63;
    const int wv   = tid >> 6;
    const float* __restrict__ src = in + (size_t)blockIdx.x * 4096;
    float* __restrict__ dst = out + (size_t)blockIdx.x * 4096;

    // Stage: 16 chunks of 1 KB; global chunk ci -> lds rows (ci*4+1 ..).
#pragma unroll
    for (int k = 0; k < 4; ++k) {
        const int ci = wv * 4 + k;                       // 0..15
        gload_lds16(src + ci * 256 + lane * 4, &img[64 + ci * 256]);
    }
    // Zero the two halo rows (rows 0 and 65).
    if (tid < 64)        img[tid] = 0.0f;
    else if (tid < 128)  img[65 * 64 + (tid - 64)] = 0.0f;

    // Uniform prep overlaps load latency.
    const float wf = fminf(fmaxf(wfac_p[0], 1.0f), 255.0f);
    float wr[9];
#pragma unroll
    for (int i = 0; i < 9; ++i)
        wr[i] = fminf(fmaxf(weight[i], -1.0f), 1.0f) * wf;
    const float invscale = 1.0f / scale_p[0];

    __syncthreads();   // waits vmcnt (gload_lds) + lgkmcnt (halo writes)

    const int c = tid & 15;   // col block: cols 4c..4c+3
    const int R = tid >> 4;   // row block: rows 4R..4R+3

    // 6 conflict-free ds_read_b128; lds row = (global row rr)+1 = 4R+k, no clamp.
    vf4 m[6];
#pragma unroll
    for (int k = 0; k < 6; ++k)
        m[k] = *(const vf4*)&img[(4 * R + k) * 64 + 4 * c];

    // Window expansion: horizontal halo via intra-16-lane shuffle only.
    float w6[6][6];
#pragma unroll
    for (int k = 0; k < 6; ++k) {
        float lft = __shfl_up(m[k].w, 1, 16);    // lane c-1's col 4c-1
        float rgt = __shfl_down(m[k].x, 1, 16);  // lane c+1's col 4c+4
        w6[k][0] = (c == 0)  ? 0.0f : lft;
        w6[k][1] = m[k].x;
        w6[k][2] = m[k].y;
        w6[k][3] = m[k].z;
        w6[k][4] = m[k].w;
        w6[k][5] = (c == 15) ? 0.0f : rgt;
    }

    // 3x3 cross-correlation with wr and wr^T, g = |gx|+|gy|.
    float g[4][4];
    float gmn = __builtin_inff(), gmx = -__builtin_inff();
#pragma unroll
    for (int i = 0; i < 4; ++i) {
#pragma unroll
        for (int j = 0; j < 4; ++j) {
            float gx = 0.0f, gy = 0.0f;
#pragma unroll
            for (int dr = 0; dr < 3; ++dr) {
#pragma unroll
                for (int dc = 0; dc < 3; ++dc) {
                    const float a = w6[i + dr][j + dc];
                    gx = fmaf(a, wr[dr * 3 + dc], gx);
                    gy = fmaf(a, wr[dc * 3 + dr], gy);
                }
            }
            const float gv = fabsf(gx) + fabsf(gy);
            g[i][j] = gv;
            gmn = fminf(gmn, gv);
            gmx = fmaxf(gmx, gv);
        }
    }

    // Per-image min/max: 64-lane butterfly, then 4 waves via LDS.
#pragma unroll
    for (int off = 32; off > 0; off >>= 1) {
        gmn = fminf(gmn, __shfl_xor(gmn, off));
        gmx = fmaxf(gmx, __shfl_xor(gmx, off));
    }
    if (lane == 0) { smin[wv] = gmn; smax[wv] = gmx; }
    __syncthreads();
    gmn = fminf(fminf(smin[0], smin[1]), fminf(smin[2], smin[3]));
    gmx = fmaxf(fmaxf(smax[0], smax[1]), fmaxf(smax[2], smax[3]));

    const float inv = 255.0f / fmaxf(gmx - gmn, 1.0f);

    // Normal cacheable float4 stores (output set stays L3-resident).
#pragma unroll
    for (int i = 0; i < 4; ++i) {
        vf4 o;
        o.x = floorf((g[i][0] - gmn) * inv) * invscale;
        o.y = floorf((g[i][1] - gmn) * inv) * invscale;
        o.z = floorf((g[i][2] - gmn) * inv) * invscale;
        o.w = floorf((g[i][3] - gmn) * inv) * invscale;
        *(vf4*)&dst[(4 * R + i) * 64 + 4 * c] = o;
    }
}

extern "C" void kernel_launch(void* const* d_in, const int* in_sizes, int n_in,
                              void* d_out, int out_size, void* d_ws, size_t ws_size,
                              hipStream_t stream) {
    const float* inp   = (const float*)d_in[0];
    const float* wgt   = (const float*)d_in[1];
    const float* wfac  = (const float*)d_in[2];
    const float* scale = (const float*)d_in[3];
    float* out = (float*)d_out;

    sobel_v8<<<2048, 256, 0, stream>>>(inp, wgt, wfac, scale, out);
}

// Round 10
// 13.534 us; speedup vs baseline: 1.2236x; 1.2236x over previous
//
#include <hip/hip_runtime.h>

typedef float vf4 __attribute__((ext_vector_type(4)));

// Async global->LDS, 16B per lane, wave-uniform LDS base (HW: base + lane*16).
__device__ __forceinline__ void gload_lds16(const void* g, void* l) {
    __builtin_amdgcn_global_load_lds(
        (const __attribute__((address_space(1))) void*)g,
        (__attribute__((address_space(3))) void*)l,
        16, 0, 0);
}

// One block per 64x64 image, 256 threads.
// v9 = v8 (zero-halo LDS rows, no vertical clamp/mask VALU) + v7's
// NONTEMPORAL stores (R8 lesson: normal stores thrash L2 write-allocate,
// +2.5us; write-once output must stream past L2).
__global__ __launch_bounds__(256) void sobel_v9(
    const float* __restrict__ in,      // (2048,1,64,64)
    const float* __restrict__ weight,  // (1,9)
    const float* __restrict__ wfac_p,  // (1,)
    const float* __restrict__ scale_p, // (1,1)
    float* __restrict__ out)
{
    __shared__ __align__(16) float img[66 * 64];   // halo rows 0 and 65, 16.9 KB
    __shared__ float smin[4], smax[4];

    const int tid  = threadIdx.x;
    const int lane = tid & 63;
    const int wv   = tid >> 6;
    const float* __restrict__ src = in + (size_t)blockIdx.x * 4096;
    float* __restrict__ dst = out + (size_t)blockIdx.x * 4096;

    // Stage: 16 chunks of 1 KB; global chunk ci -> lds rows (ci*4+1 ..).
#pragma unroll
    for (int k = 0; k < 4; ++k) {
        const int ci = wv * 4 + k;                       // 0..15
        gload_lds16(src + ci * 256 + lane * 4, &img[64 + ci * 256]);
    }
    // Zero the two halo rows (rows 0 and 65).
    if (tid < 64)        img[tid] = 0.0f;
    else if (tid < 128)  img[65 * 64 + (tid - 64)] = 0.0f;

    // Uniform prep overlaps load latency.
    const float wf = fminf(fmaxf(wfac_p[0], 1.0f), 255.0f);
    float wr[9];
#pragma unroll
    for (int i = 0; i < 9; ++i)
        wr[i] = fminf(fmaxf(weight[i], -1.0f), 1.0f) * wf;
    const float invscale = 1.0f / scale_p[0];

    __syncthreads();   // waits vmcnt (gload_lds) + lgkmcnt (halo writes)

    const int c = tid & 15;   // col block: cols 4c..4c+3
    const int R = tid >> 4;   // row block: rows 4R..4R+3

    // 6 ds_read_b128; lds row = (global row)+1 = 4R+k, no clamp, no mask.
    vf4 m[6];
#pragma unroll
    for (int k = 0; k < 6; ++k)
        m[k] = *(const vf4*)&img[(4 * R + k) * 64 + 4 * c];

    // Window expansion: horizontal halo via intra-16-lane shuffle only.
    float w6[6][6];
#pragma unroll
    for (int k = 0; k < 6; ++k) {
        float lft = __shfl_up(m[k].w, 1, 16);    // lane c-1's col 4c-1
        float rgt = __shfl_down(m[k].x, 1, 16);  // lane c+1's col 4c+4
        w6[k][0] = (c == 0)  ? 0.0f : lft;
        w6[k][1] = m[k].x;
        w6[k][2] = m[k].y;
        w6[k][3] = m[k].z;
        w6[k][4] = m[k].w;
        w6[k][5] = (c == 15) ? 0.0f : rgt;
    }

    // 3x3 cross-correlation with wr and wr^T, g = |gx|+|gy|.
    float g[4][4];
    float gmn = __builtin_inff(), gmx = -__builtin_inff();
#pragma unroll
    for (int i = 0; i < 4; ++i) {
#pragma unroll
        for (int j = 0; j < 4; ++j) {
            float gx = 0.0f, gy = 0.0f;
#pragma unroll
            for (int dr = 0; dr < 3; ++dr) {
#pragma unroll
                for (int dc = 0; dc < 3; ++dc) {
                    const float a = w6[i + dr][j + dc];
                    gx = fmaf(a, wr[dr * 3 + dc], gx);
                    gy = fmaf(a, wr[dc * 3 + dr], gy);
                }
            }
            const float gv = fabsf(gx) + fabsf(gy);
            g[i][j] = gv;
            gmn = fminf(gmn, gv);
            gmx = fmaxf(gmx, gv);
        }
    }

    // Per-image min/max: 64-lane butterfly, then 4 waves via LDS.
#pragma unroll
    for (int off = 32; off > 0; off >>= 1) {
        gmn = fminf(gmn, __shfl_xor(gmn, off));
        gmx = fmaxf(gmx, __shfl_xor(gmx, off));
    }
    if (lane == 0) { smin[wv] = gmn; smax[wv] = gmx; }
    __syncthreads();
    gmn = fminf(fminf(smin[0], smin[1]), fminf(smin[2], smin[3]));
    gmx = fmaxf(fmaxf(smax[0], smax[1]), fmaxf(smax[2], smax[3]));

    const float inv = 255.0f / fmaxf(gmx - gmn, 1.0f);

    // Nontemporal float4 stores (stream past L2; output never re-read).
#pragma unroll
    for (int i = 0; i < 4; ++i) {
        vf4 o;
        o.x = floorf((g[i][0] - gmn) * inv) * invscale;
        o.y = floorf((g[i][1] - gmn) * inv) * invscale;
        o.z = floorf((g[i][2] - gmn) * inv) * invscale;
        o.w = floorf((g[i][3] - gmn) * inv) * invscale;
        __builtin_nontemporal_store(o, (vf4*)&dst[(4 * R + i) * 64 + 4 * c]);
    }
}

extern "C" void kernel_launch(void* const* d_in, const int* in_sizes, int n_in,
                              void* d_out, int out_size, void* d_ws, size_t ws_size,
                              hipStream_t stream) {
    const float* inp   = (const float*)d_in[0];
    const float* wgt   = (const float*)d_in[1];
    const float* wfac  = (const float*)d_in[2];
    const float* scale = (const float*)d_in[3];
    float* out = (float*)d_out;

    sobel_v9<<<2048, 256, 0, stream>>>(inp, wgt, wfac, scale, out);
}